// Round 4
// baseline (44.346 us; speedup 1.0000x reference)
//
#include <hip/hip_runtime.h>

// arDCA: out[n,q] = softmax_q( h[400,q] + sum_{j<400} J[400,q,j,tok(n,j)] )
// K0: Jq2[j][t][q] <- J[400,q,j,t]    (705 KB, L2-resident per XCD)
// K1: single fused kernel: 683 blocks x 128 thr, NT=6 n-rows each, 25 async
//     double-buffered stages of 16 j (global_load_lds w16, counted vmcnt),
//     tokenize + L2 gather-accumulate + in-block softmax -> out. No partials.
// N=4096, RES=400, Q=21, L=512.

#define QA    21
#define RESI  400
#define NSEQ  4096
#define NT    6                  // n per block
#define NBX   683                // ceil(4096/6)
#define SJ    16                 // j per stage
#define NST   25                 // stages (25*16 = 400)
#define STAGE_F  (NT*SJ*QA)      // 2016 floats (8064 B)
#define STAGE_V4 (STAGE_F/4)     // 504 dwordx4
#define JQ2_ELEMS (RESI*QA*QA)   // 176400

#define GLOAD_LDS16(g, l)                                                     \
    __builtin_amdgcn_global_load_lds(                                         \
        (const __attribute__((address_space(1))) void*)(g),                   \
        (__attribute__((address_space(3))) void*)(l), 16, 0, 0)

// ---------------- K0: Jq2[(j*21+a)*21+q] = J[((8400+q)*512+j)*21+a] --------
__global__ __launch_bounds__(256) void k0_jq2(const float* __restrict__ J,
                                              float* __restrict__ Jq2) {
    int s = blockIdx.x * 256 + threadIdx.x;
    if (s >= JQ2_ELEMS) return;
    int q  = s / 8400;            // 0..20
    int ja = s - q * 8400;        // j*21+a, contiguous -> coalesced read
    Jq2[ja * 21 + q] = J[(8400 + q) * 10752 + ja];
}

// ---------------- K1: fully fused ------------------------------------------
__global__ __launch_bounds__(128) void k1_main(const float* __restrict__ X,
                                               const float* __restrict__ Jq2,
                                               const float* __restrict__ h,
                                               float* __restrict__ out) {
    __shared__ float buf[2][STAGE_F];     // 16128 B
    __shared__ int   tokb[2][NT * SJ];    // 768 B
    __shared__ float lg[NT * QA];         // 504 B

    const int tid = threadIdx.x;
    const int n0  = blockIdx.x * NT;

    const int w    = tid >> 6, l = tid & 63;
    const int q    = l % 21;
    const int ns   = l / 21;              // 0..2 valid
    const int nloc = w * 3 + ns;          // 0..5
    const bool act = (l < 63);

    // issue one stage's 504 dwordx4 via global_load_lds (4 instr/thread)
    auto issue = [&](int s) {
        const int jb = s * SJ;
        float* dst = &buf[s & 1][0];
        #pragma unroll
        for (int k = 0; k < 4; ++k) {
            int e = tid + (k << 7);
            if (e < STAGE_V4) {           // k<3 always true; k==3: tid<120
                int row = e / 84;         // 84 dwordx4 per n-row
                int col = e - row * 84;
                int nr  = n0 + row;
                if (nr >= NSEQ) nr = n0;  // tail clamp (data unused)
                const float* gp = X + (nr * RESI + jb) * QA + (col << 2);
                GLOAD_LDS16(gp, dst + (e << 2));
            }
        }
    };

    float acc = 0.f;
    issue(0);

    for (int s = 0; s < NST; ++s) {
        const int p = s & 1;
        if (s + 1 < NST) {
            issue(s + 1);
            asm volatile("s_waitcnt vmcnt(4)" ::: "memory");  // stage s landed
        } else {
            asm volatile("s_waitcnt vmcnt(0)" ::: "memory");
        }
        __builtin_amdgcn_s_barrier();
        __builtin_amdgcn_sched_barrier(0);

        // tokenize: 96 cells, one per thread; iota-dot exact for one-hot
        if (tid < NT * SJ) {
            const int r = tid >> 4, jj = tid & 15;
            const float* cell = &buf[p][r * (SJ * QA) + jj * QA];
            float fa = 0.f;
            #pragma unroll
            for (int a = 0; a < QA; ++a) fa = fmaf(cell[a], (float)a, fa);
            tokb[p][tid] = (int)(fa + 0.5f);
        }
        asm volatile("s_waitcnt lgkmcnt(0)" ::: "memory");
        __builtin_amdgcn_s_barrier();
        __builtin_amdgcn_sched_barrier(0);

        // accumulate: per wave 21q x 3n; gather = 3 runs of 84B, L2-hot Jq2
        if (act) {
            const int jb441 = s * (SJ * 441);
            const int4* tp = (const int4*)&tokb[p][nloc * SJ];
            #pragma unroll
            for (int g = 0; g < 4; ++g) {
                int4 t4 = tp[g];
                acc += Jq2[jb441 + (4 * g + 0) * 441 + t4.x * 21 + q];
                acc += Jq2[jb441 + (4 * g + 1) * 441 + t4.y * 21 + q];
                acc += Jq2[jb441 + (4 * g + 2) * 441 + t4.z * 21 + q];
                acc += Jq2[jb441 + (4 * g + 3) * 441 + t4.w * 21 + q];
            }
        }
    }

    // in-block softmax + coalesced out
    if (act) lg[nloc * QA + q] = acc + h[8400 + q];
    __syncthreads();
    if (tid < NT * QA) {
        const int nl = tid / QA, q2 = tid - nl * QA;
        const int n  = n0 + nl;
        if (n < NSEQ) {
            const float* rowp = lg + nl * QA;
            float m = -1e30f;
            #pragma unroll
            for (int a = 0; a < QA; ++a) m = fmaxf(m, rowp[a]);
            float den = 0.f;
            #pragma unroll
            for (int a = 0; a < QA; ++a) den += __expf(rowp[a] - m);
            out[n * QA + q2] = __expf(rowp[q2] - m) / den;
        }
    }
}

extern "C" void kernel_launch(void* const* d_in, const int* in_sizes, int n_in,
                              void* d_out, int out_size, void* d_ws, size_t ws_size,
                              hipStream_t stream) {
    const float* X = (const float*)d_in[0];   // [4096,400,21] one-hot
    const float* h = (const float*)d_in[1];   // [512,21]
    const float* J = (const float*)d_in[2];   // [512,21,512,21]
    float* out = (float*)d_out;               // [4096,21]

    float* Jq2 = (float*)d_ws;                // 176400 floats (~706 KB)

    k0_jq2<<<(JQ2_ELEMS + 255) / 256, 256, 0, stream>>>(J, Jq2);
    k1_main<<<NBX, 128, 0, stream>>>(X, Jq2, h, out);
}

// Round 5
// 42.547 us; speedup vs baseline: 1.0423x; 1.0423x over previous
//
#include <hip/hip_runtime.h>

// arDCA: out[n,q] = softmax_q( h[400,q] + sum_{j<400} J[400,q,j,tok(n,j)] )
// K0: Jq2[j][t][q] <- J[400,q,j,t]   (705 KB, L2-resident)
// K1: barrier-free wave-private pipeline. Block=128thr=2 waves, owns 3 n.
//     Wave w handles j in [w*200, w*200+200), 10 stages of 20 j.
//     Per stage: linear ds_read tokenize (one-hot -> direct token ds_write),
//     L2 gather-accumulate, prefetch s+2 issued AFTER gathers (counted vmcnt,
//     no FIFO drain). In-block softmax epilogue.
// N=4096, RES=400, Q=21, L=512.

#define QA      21
#define RESI    400
#define NSEQ    4096
#define ROWS    3                // n per block
#define SJ      20               // j per stage
#define NST     10               // stages per wave (200 j)
#define STAGE_F 1260             // ROWS*SJ*QA floats (5040 B)
#define NBX     1366             // ceil(4096/3)
#define JQ2_ELEMS (RESI*QA*QA)   // 176400

#define GLOAD_LDS16(g, l)                                                     \
    __builtin_amdgcn_global_load_lds(                                         \
        (const __attribute__((address_space(1))) void*)(g),                   \
        (__attribute__((address_space(3))) void*)(l), 16, 0, 0)

// ---------------- K0: Jq2[(j*21+a)*21+q] = J[((8400+q)*512+j)*21+a] --------
__global__ __launch_bounds__(256) void k0_jq2(const float* __restrict__ J,
                                              float* __restrict__ Jq2) {
    int s = blockIdx.x * 256 + threadIdx.x;
    if (s >= JQ2_ELEMS) return;
    int q  = s / 8400;            // 0..20
    int ja = s - q * 8400;        // j*21+a, contiguous -> coalesced read
    Jq2[ja * 21 + q] = J[(8400 + q) * 10752 + ja];
}

// ---------------- K1: barrier-free fused kernel ----------------------------
__global__ __launch_bounds__(128) void k1_main(const float* __restrict__ X,
                                               const float* __restrict__ Jq2,
                                               const float* __restrict__ h,
                                               float* __restrict__ out) {
    __shared__ float buf[2][2][STAGE_F];   // [wave][slot][1260]  20160 B
    __shared__ int   tokb[2][64];          // [wave][60 cells + 4 pad]
    __shared__ float comb[2][63];          // per-wave partials
    __shared__ float lg[64];               // combined logits [ns*21+q]

    const int tid   = threadIdx.x;
    const int w     = tid >> 6;            // wave = j-split half
    const int L     = tid & 63;
    const int n0    = blockIdx.x * ROWS;
    const int jbase = w * (SJ * NST);      // 0 or 200

    // ---- per-lane prefetch source pointers (chunk e = k*64+L of 315) ----
    // stage bytes: [3 rows][20 j][21 a] ; row = e/105 (105 x 16B per row)
    const char* Xb = (const char*)X;
    const char* ps[5];
    bool pv[5];
    #pragma unroll
    for (int k = 0; k < 5; ++k) {
        int e   = k * 64 + L;
        pv[k]   = (e < 315);
        int row = e / 105;
        int col = e - row * 105;
        int nr  = n0 + row; if (nr > NSEQ - 1) nr = NSEQ - 1;   // tail clamp
        ps[k] = Xb + (size_t)nr * 33600 + (size_t)jbase * 84 + (size_t)col * 16;
    }

    // ---- per-lane tokenize map: round r covers stage dwords r*64+L ----
    int pcell[20], pa[20];
    #pragma unroll
    for (int r = 0; r < 20; ++r) {
        int d = r * 64 + L;
        int c = d / 21;
        int a = d - c * 21;
        if (d >= STAGE_F) { c = 60 + (L & 3); a = 0; }   // pad cells 60..63
        pcell[r] = c; pa[r] = a;
    }

    const int  gq   = L % 21;
    const int  gns  = L / 21;              // 0..2 valid
    const bool gact = (L < 63);

    auto prefetch = [&](int s) {
        char* dst0 = (char*)&buf[w][s & 1][0];
        #pragma unroll
        for (int k = 0; k < 5; ++k)
            if (pv[k])
                GLOAD_LDS16(ps[k] + s * 1680, dst0 + (k * 64 + L) * 16);
    };

    prefetch(0);
    prefetch(1);

    float acc = 0.f;

    for (int s = 0; s < NST; ++s) {
        // buf[s] guaranteed landed once <=5 outstanding (they are buf[s+1])
        asm volatile("s_waitcnt vmcnt(5)" ::: "memory");
        __builtin_amdgcn_sched_barrier(0);

        // ---- tokenize: linear b32 reads (bank-free), one-hot direct write
        const float* lb = &buf[w][s & 1][0] + L;
        #pragma unroll
        for (int r = 0; r < 20; ++r) {
            float v = lb[r * 64];          // ds_read_b32, offset r*256
            if (v > 0.5f) tokb[w][pcell[r]] = pa[r];
        }
        asm volatile("s_waitcnt lgkmcnt(0)" ::: "memory");
        __builtin_amdgcn_sched_barrier(0);

        // ---- gather from L2-hot Jq2 (3 runs of 84B per load instr) ----
        float gv[20];
        if (gact) {
            int t[20];
            const int4* tp = (const int4*)&tokb[w][gns * 20];
            #pragma unroll
            for (int g = 0; g < 5; ++g) {
                int4 t4 = tp[g];
                t[4*g+0] = t4.x; t[4*g+1] = t4.y;
                t[4*g+2] = t4.z; t[4*g+3] = t4.w;
            }
            const float* Jr = Jq2 + (jbase + s * SJ) * 441 + gq;
            #pragma unroll
            for (int jj = 0; jj < 20; ++jj)
                gv[jj] = Jr[jj * 441 + t[jj] * 21];
        }
        // pin order: gathers above, prefetch here, adds below -> adds get a
        // counted vmcnt (prefetch stays in flight, no drain)
        __builtin_amdgcn_sched_barrier(0);
        if (s + 2 < NST) prefetch(s + 2);
        __builtin_amdgcn_sched_barrier(0);
        if (gact) {
            #pragma unroll
            for (int jj = 0; jj < 20; ++jj) acc += gv[jj];
        }
    }

    // ---- combine 2 waves + softmax (only sync in the kernel) ----
    if (gact) comb[w][L] = acc;
    __syncthreads();
    if (tid < 63)
        lg[tid] = comb[0][tid] + comb[1][tid] + h[8400 + tid % 21];
    __syncthreads();
    if (tid < 63) {
        const int ns = tid / 21, q = tid - ns * 21;
        const int n  = n0 + ns;
        if (n < NSEQ) {
            const float* r = lg + ns * 21;
            float m = -1e30f;
            #pragma unroll
            for (int a = 0; a < QA; ++a) m = fmaxf(m, r[a]);
            float den = 0.f;
            #pragma unroll
            for (int a = 0; a < QA; ++a) den += __expf(r[a] - m);
            out[n * QA + q] = __expf(r[q] - m) / den;
        }
    }
}

extern "C" void kernel_launch(void* const* d_in, const int* in_sizes, int n_in,
                              void* d_out, int out_size, void* d_ws, size_t ws_size,
                              hipStream_t stream) {
    const float* X = (const float*)d_in[0];   // [4096,400,21] one-hot
    const float* h = (const float*)d_in[1];   // [512,21]
    const float* J = (const float*)d_in[2];   // [512,21,512,21]
    float* out = (float*)d_out;               // [4096,21]

    float* Jq2 = (float*)d_ws;                // 176400 floats (~706 KB)

    k0_jq2<<<(JQ2_ELEMS + 255) / 256, 256, 0, stream>>>(J, Jq2);
    k1_main<<<NBX, 128, 0, stream>>>(X, Jq2, h, out);
}

// Round 6
// 40.194 us; speedup vs baseline: 1.1033x; 1.0585x over previous
//
#include <hip/hip_runtime.h>

// arDCA: out[n,q] = softmax_q( h[400,q] + sum_{j<400} J[400,q,j,tok(n,j)] )
// R6 = R3 structure with 2x occupancy: SJ 16->8 => LDS 33->16.9 KB =>
// 9 blocks/CU cap => entire 1710-block grid resident (26.7 waves/CU).
// K0: Jq2[j][t][q] <- J[400,q,j,t]   (705 KB, L2-resident)
// K1: fused tokenize+gather-accumulate, async double-buffered X staging,
//     counted vmcnt, partials P[c][tile][252]
// K2: reduce partials + h + softmax, coalesced.
// N=4096, RES=400, Q=21, L=512.

#define QA    21
#define RESI  400
#define NSEQ  4096
#define NT    12                 // n per block
#define NBX   342                // ceil(4096/12)
#define NCH   5                  // j-chunks
#define CHJ   80                 // j per chunk
#define SJ    8                  // j per stage
#define NST   10                 // stages per chunk
#define STAGE_F  (NT*SJ*QA)      // 2016 floats (8064 B)
#define STAGE_V4 (STAGE_F/4)     // 504 dwordx4 per stage
#define JQ2_ELEMS (RESI*QA*QA)   // 176400
#define P_PER (NT*QA)            // 252
#define P_ELEMS (NCH*NBX*P_PER)  // 430920

#define GLOAD_LDS16(g, l)                                                     \
    __builtin_amdgcn_global_load_lds(                                         \
        (const __attribute__((address_space(1))) void*)(g),                   \
        (__attribute__((address_space(3))) void*)(l), 16, 0, 0)

// ---------------- K0: Jq2[(j*21+a)*21+q] = J[((8400+q)*512+j)*21+a] --------
__global__ __launch_bounds__(256) void k0_jq2(const float* __restrict__ J,
                                              float* __restrict__ Jq2) {
    int s = blockIdx.x * 256 + threadIdx.x;
    if (s >= JQ2_ELEMS) return;
    int q  = s / 8400;            // 0..20
    int ja = s - q * 8400;        // j*21+a, contiguous -> coalesced read
    Jq2[ja * 21 + q] = J[(8400 + q) * 10752 + ja];
}

// ---------------- K1: fused tokenize + accumulate --------------------------
// block: 256 thr (4 waves); tile = 12 n x 80 j, 10 stages of 8 j.
__global__ __launch_bounds__(256) void k1_main(const float* __restrict__ X,
                                               const float* __restrict__ Jq2,
                                               float* __restrict__ P) {
    __shared__ float buf[2][STAGE_F];     // 16128 B
    __shared__ int   tokb[2][NT * SJ];    // 768 B

    const int tid = threadIdx.x;
    const int bx  = blockIdx.x;
    const int c   = blockIdx.y;
    const int n0  = bx * NT;
    const int j0  = c * CHJ;

    const int w    = tid >> 6, l = tid & 63;
    const int q    = l % 21;
    const int ns   = l / 21;              // 0..2 valid
    const int nloc = w * 3 + ns;          // 0..11
    const bool act = (l < 63);

    // issue one stage's 504 dwordx4 via global_load_lds (2 instr/thread)
    auto issue = [&](int s) {
        const int jb = j0 + s * SJ;
        float* dst = &buf[s & 1][0];
        #pragma unroll
        for (int k = 0; k < 2; ++k) {
            int e = tid + (k << 8);
            if (e < STAGE_V4) {           // k==0 always; k==1: tid<248
                int row = e / 42;         // 42 dwordx4 per n-row (672 B)
                int col = e - row * 42;
                int nr  = n0 + row;
                if (nr >= NSEQ) nr = n0;  // tail clamp (data unused)
                const float* gp = X + (nr * RESI + jb) * QA + (col << 2);
                GLOAD_LDS16(gp, dst + (e << 2));
            }
        }
    };

    float acc = 0.f;
    issue(0);

    #pragma unroll
    for (int s = 0; s < NST; ++s) {
        const int p = s & 1;
        if (s + 1 < NST) {
            issue(s + 1);
            asm volatile("s_waitcnt vmcnt(2)" ::: "memory");  // stage s landed
        } else {
            asm volatile("s_waitcnt vmcnt(0)" ::: "memory");
        }
        __builtin_amdgcn_s_barrier();
        __builtin_amdgcn_sched_barrier(0);

        // tokenize: 96 cells, one per thread; iota-dot exact for one-hot
        if (tid < NT * SJ) {
            const int r = tid >> 3, jj = tid & 7;
            const float* cell = &buf[p][r * (SJ * QA) + jj * QA];
            float fa = 0.f;
            #pragma unroll
            for (int a = 0; a < QA; ++a) fa = fmaf(cell[a], (float)a, fa);
            tokb[p][tid] = (int)(fa + 0.5f);
        }
        asm volatile("s_waitcnt lgkmcnt(0)" ::: "memory");
        __builtin_amdgcn_s_barrier();
        __builtin_amdgcn_sched_barrier(0);

        // accumulate: per wave 21q x 3n; gather = 3 runs of 84B, L2-hot Jq2
        if (act) {
            const int jb441 = (j0 + s * SJ) * 441;
            const int4* tp = (const int4*)&tokb[p][nloc * SJ];
            #pragma unroll
            for (int g = 0; g < 2; ++g) {
                int4 t4 = tp[g];
                acc += Jq2[jb441 + (4 * g + 0) * 441 + t4.x * 21 + q];
                acc += Jq2[jb441 + (4 * g + 1) * 441 + t4.y * 21 + q];
                acc += Jq2[jb441 + (4 * g + 2) * 441 + t4.z * 21 + q];
                acc += Jq2[jb441 + (4 * g + 3) * 441 + t4.w * 21 + q];
            }
        }
    }

    // partial write via LDS bounce (buf free after last stage)
    float* pb = &buf[0][0];
    __builtin_amdgcn_s_barrier();
    if (act) pb[q * NT + nloc] = acc;
    __syncthreads();
    if (tid < P_PER)
        P[(c * NBX + bx) * P_PER + tid] = pb[tid];   // coalesced
}

// ---------------- K2: reduce partials + h + softmax ------------------------
__global__ __launch_bounds__(256) void k2_finish(const float* __restrict__ P,
                                                 const float* __restrict__ h,
                                                 float* __restrict__ out) {
    __shared__ float sm[P_PER];          // [q][nl] layout, q*12+nl
    const int bx = blockIdx.x, tid = threadIdx.x;
    if (tid < P_PER) {
        float v = 0.f;
        #pragma unroll
        for (int cc = 0; cc < NCH; ++cc)
            v += P[(cc * NBX + bx) * P_PER + tid];   // coalesced
        sm[tid] = v + h[8400 + tid / NT];
    }
    __syncthreads();
    if (tid < P_PER) {
        const int nl = tid / QA, q2 = tid - nl * QA;
        const int n  = bx * NT + nl;
        if (n < NSEQ) {
            float m = -1e30f;
            #pragma unroll
            for (int a = 0; a < QA; ++a) m = fmaxf(m, sm[a * NT + nl]);
            float den = 0.f;
            #pragma unroll
            for (int a = 0; a < QA; ++a) den += __expf(sm[a * NT + nl] - m);
            out[n * QA + q2] = __expf(sm[q2 * NT + nl] - m) / den;  // coalesced
        }
    }
}

extern "C" void kernel_launch(void* const* d_in, const int* in_sizes, int n_in,
                              void* d_out, int out_size, void* d_ws, size_t ws_size,
                              hipStream_t stream) {
    const float* X = (const float*)d_in[0];   // [4096,400,21] one-hot
    const float* h = (const float*)d_in[1];   // [512,21]
    const float* J = (const float*)d_in[2];   // [512,21,512,21]
    float* out = (float*)d_out;               // [4096,21]

    float* Jq2 = (float*)d_ws;                // 176400 floats
    float* P   = Jq2 + JQ2_ELEMS;             // 430920 floats (~2.43 MB total)

    k0_jq2<<<(JQ2_ELEMS + 255) / 256, 256, 0, stream>>>(J, Jq2);
    k1_main<<<dim3(NBX, NCH), 256, 0, stream>>>(X, Jq2, P);
    k2_finish<<<NBX, 256, 0, stream>>>(P, h, out);
}